// Round 11
// baseline (201.123 us; speedup 1.0000x reference)
//
#include <hip/hip_runtime.h>
#include <hip/hip_bf16.h>
#include <stdint.h>

#define M_TOT 16384     // B*P = 64*256
#define DM 768
#define BM 128
#define BN 192
#define NKT3 12         // K / 64
#define QOFF (128 * DM) // sumsq offset in bnpart (floats)

typedef __attribute__((ext_vector_type(4))) float f32x4;
typedef __attribute__((ext_vector_type(8))) short short8;
typedef __attribute__((ext_vector_type(8))) unsigned short ushort8;
typedef __attribute__((ext_vector_type(4))) unsigned short ushort4v;

__device__ __forceinline__ unsigned short f2bf(float f) {
    union { float f; unsigned u; } v; v.f = f;
    unsigned r = v.u + 0x7fffu + ((v.u >> 16) & 1u);
    return (unsigned short)(r >> 16);
}
__device__ __forceinline__ float bf2f(unsigned short h) {
    union { unsigned u; float f; } v; v.u = ((unsigned)h) << 16;
    return v.f;
}

__device__ __forceinline__ void gload_lds16(const unsigned short* g, unsigned short* l) {
    __builtin_amdgcn_global_load_lds(
        (const __attribute__((address_space(1))) void*)g,
        (__attribute__((address_space(3))) void*)l, 16, 0, 0);
}

// ---------------- prep: weight cvt + inverse permutation + pos->bf16 ----------------
__global__ __launch_bounds__(256)
void prepw(const float* __restrict__ cw, const float* __restrict__ w1,
           const float* __restrict__ mw, const int* __restrict__ perm,
           const float* __restrict__ pos,
           unsigned short* __restrict__ wA, unsigned short* __restrict__ wD,
           unsigned short* __restrict__ wM, int* __restrict__ invp,
           unsigned short* __restrict__ posb)
{
    int b = blockIdx.x;
    if (b < 2880) {
        int i = b * 256 + threadIdx.x;          // 737280 vec4 groups
        const float* src; unsigned short* dst; int off;
        if (i < 147456)              { src = cw; dst = wA; off = i; }
        else if (i < 147456+442368)  { src = w1; dst = wD; off = i - 147456; }
        else                         { src = mw; dst = wM; off = i - 589824; }
        f32x4 v = ((const f32x4*)src)[off];
        ushort4v o;
        o.x = f2bf(v.x); o.y = f2bf(v.y); o.z = f2bf(v.z); o.w = f2bf(v.w);
        ((ushort4v*)dst)[off] = o;
    } else if (b < 2944) {
        int i = (b - 2880) * 256 + threadIdx.x;  // 16384
        int bb = i >> 8;
        invp[(bb << 8) + perm[i]] = i & 255;
    } else {
        int i = (b - 2944) * 256 + threadIdx.x;  // 49152 vec4 groups (pos)
        f32x4 v = ((const f32x4*)pos)[i];
        ushort4v o;
        o.x = f2bf(v.x); o.y = f2bf(v.y); o.z = f2bf(v.z); o.w = f2bf(v.w);
        ((ushort4v*)posb)[i] = o;
    }
}

// =====================================================================
// GEMM: out[M,768] = T(A)[M,768] * Bw[768,768]^T + bias
//   XF=0: A bf16, staged via global_load_lds (identity)
//   XF=1: A bf16 reg-staged (dbuf'd early ALOAD), T = relu(scl*a+shf)
//   XF=2: as XF=1 plus prefetched bf16 pos: T = relu(relu(scl*a+shf)+pos)
//   XF=3: A = x f32, reg-staged im2col + cvt (patch embed)
// BM=128 x BN=192, BK=64, 4 waves 1M x 4N, wave tile 128x48,
// 16x16x32 MFMA, 2-deep dbuf, 80 KB LDS -> 2 blocks/CU.
// EPI 0: relu->bf16 ; EPI 1: ->bf16 + BN column partials ; EPI 2: perm-scatter->f32
// =====================================================================
#define VM0  asm volatile("s_waitcnt vmcnt(0)" ::: "memory");
#define LGKM0 asm volatile("s_waitcnt lgkmcnt(0)" ::: "memory");
#define BARR asm volatile("s_barrier" ::: "memory");

// phase: [opt B-frag loads] + A-frag loads + PRE + MFMA(12) + POST + barrier
#define PH(AB, BB, MH, KS, LOADB, PRE, POST)                                     \
  {                                                                              \
    if (LOADB) {                                                                 \
      _Pragma("unroll")                                                          \
      for (int j = 0; j < 3; ++j)                                                \
        breg[j] = *(const short8*)((const char*)Bb + (size_t)(BB) * (BN*64*2) +  \
                  (wc * 48 + j * 16 + frow) * 128 + (((KS) * 64 + fq16) ^ rswz));\
    }                                                                            \
    short8 af[4];                                                                \
    _Pragma("unroll")                                                            \
    for (int i = 0; i < 4; ++i)                                                  \
      af[i] = *(const short8*)((const char*)Aa + (size_t)(AB) * (BM*64*2) +      \
              ((MH) * 64 + i * 16 + frow) * 128 +                                \
              (((KS) * 64 + fq16) ^ rswz));                                      \
    PRE;                                                                         \
    __builtin_amdgcn_s_setprio(1);                                               \
    _Pragma("unroll")                                                            \
    for (int i = 0; i < 4; ++i)                                                  \
      _Pragma("unroll")                                                          \
      for (int j = 0; j < 3; ++j)                                                \
        acc[(MH) * 4 + i][j] = __builtin_amdgcn_mfma_f32_16x16x32_bf16(          \
            af[i], breg[j], acc[(MH) * 4 + i][j], 0, 0, 0);                      \
    __builtin_amdgcn_s_setprio(0);                                               \
    POST;                                                                        \
    BARR                                                                         \
  }

// reg-staging: load into named set S (static indexing, rule #20)
#define ALOADM(t, S)                                                             \
  {                                                                              \
    if (XF == 3) {                                                               \
      const int c  = (t) >> 2;                                                   \
      const int r  = ((t) & 3) * 64 + (lane & 7) * 8;                            \
      const int kh = r >> 4;                                                     \
      const int kw0 = r & 15;                                                    \
      _Pragma("unroll")                                                          \
      for (int j = 0; j < 4; ++j) {                                              \
        int m = m0 + rRow0 + j * 8;                                              \
        int b = m >> 8, p = m & 255;                                             \
        const float* src = X + ((((size_t)b * 3 + c) * 256 + (p >> 4) * 16 + kh) \
                                * 256 + (p & 15) * 16 + kw0);                    \
        aldf##S[j][0] = *(const f32x4*)src;                                      \
        aldf##S[j][1] = *(const f32x4*)(src + 4);                                \
      }                                                                          \
    } else {                                                                     \
      _Pragma("unroll")                                                          \
      for (int j = 0; j < 4; ++j)                                                \
        aldr##S[j] = *(const ushort8*)(gAr + (size_t)j * 8 * DM + (t) * 64);     \
      if (XF == 2) {                                                             \
        _Pragma("unroll")                                                        \
        for (int j = 0; j < 4; ++j)                                              \
          aldp##S[j] = *(const ushort8*)(posb +                                  \
              (size_t)((m0 & 255) + rRow0 + j * 8) * DM +                        \
              (t) * 64 + (lane & 7) * 8);                                        \
      }                                                                          \
    }                                                                            \
  }

#define XFORMM(t, tb, S)                                                         \
  {                                                                              \
    if (XF == 3) {                                                               \
      _Pragma("unroll")                                                          \
      for (int j = 0; j < 4; ++j) {                                              \
        int row = rRow0 + j * 8;                                                 \
        ushort8 o;                                                               \
        _Pragma("unroll")                                                        \
        for (int e = 0; e < 8; ++e)                                              \
          o[e] = f2bf((e < 4) ? aldf##S[j][0][e] : aldf##S[j][1][e - 4]);        \
        *(ushort8*)((char*)Aa + (size_t)(tb) * (BM*64*2) + row * 128 +           \
                    (((lane & 7) * 16) ^ wrswz)) = o;                            \
      }                                                                          \
    } else {                                                                     \
      const int k0 = (t) * 64 + (lane & 7) * 8;                                  \
      f32x4 sa = *(const f32x4*)(ssA + k0);                                      \
      f32x4 sb = *(const f32x4*)(ssA + k0 + 4);                                  \
      f32x4 ha = *(const f32x4*)(ssA + DM + k0);                                 \
      f32x4 hb = *(const f32x4*)(ssA + DM + k0 + 4);                             \
      _Pragma("unroll")                                                          \
      for (int j = 0; j < 4; ++j) {                                              \
        int row = rRow0 + j * 8;                                                 \
        ushort8 u = aldr##S[j];                                                  \
        ushort8 o;                                                               \
        _Pragma("unroll")                                                        \
        for (int e = 0; e < 8; ++e) {                                            \
          float f = bf2f(u[e]);                                                  \
          float sc = (e < 4) ? sa[e] : sb[e - 4];                                \
          float sh = (e < 4) ? ha[e] : hb[e - 4];                                \
          float y = fmaxf(fmaf(sc, f, sh), 0.0f);                                \
          if (XF == 2) y = fmaxf(y + bf2f(aldp##S[j][e]), 0.0f);                 \
          o[e] = f2bf(y);                                                        \
        }                                                                        \
        *(ushort8*)((char*)Aa + (size_t)(tb) * (BM*64*2) + row * 128 +           \
                    (((lane & 7) * 16) ^ wrswz)) = o;                            \
      }                                                                          \
    }                                                                            \
  }

// one K-tile for the reg-staged path; CB = read buffer (0 even tile, 1 odd),
// LS = aldr set loaded this tile, XS = set transformed this tile
#define XTILE(kt, CB, LS, XS)                                                    \
    PH(CB, CB, 0, 0, 1, { if ((kt) < 11) STAGE_B((CB) ^ 1, (kt) + 1);            \
                          if ((kt) < 10) ALOADM((kt) + 2, LS) }, {})             \
    PH(CB, CB, 1, 0, 0, { if ((kt) < 11) XFORMM((kt) + 1, (CB) ^ 1, XS) },       \
                        { if ((kt) < 11) LGKM0 })                                \
    PH(CB, CB, 0, 1, 1, {}, {})                                                  \
    if ((kt) < 11) { PH(CB, CB, 1, 1, 0, {}, { VM0 }) }                          \
    else           { PH(CB, CB, 1, 1, 0, {}, {}) }

template<int EPI, int XF>
__global__ __launch_bounds__(256, 2)
void gemm8p(const void* __restrict__ Asrc,
            const unsigned short* __restrict__ Bw,
            const float* __restrict__ bias,
            void* __restrict__ outp,
            const int* __restrict__ invp,
            float* __restrict__ bnpart,
            const float* __restrict__ ssA,     // [scale 768 | shift 768]
            const unsigned short* __restrict__ posb)  // [256][768] bf16 (XF==2)
{
    __shared__ unsigned short Aa[2][BM * 64];   // 2 x 16 KB
    __shared__ unsigned short Bb[2][BN * 64];   // 2 x 24 KB  (total 80 KB)

    const unsigned short* A = (const unsigned short*)Asrc;
    const float* X = (const float*)Asrc;

    const int tid  = threadIdx.x;
    const int w    = tid >> 6;                  // 0..3
    const int lane = tid & 63;
    const int wc = w;                           // 1M x 4N

    // bijective XCD swizzle over exactly 512 workgroups (64 per XCD)
    int bid = blockIdx.x;
    int nb  = (bid & 7) * 64 + (bid >> 3);
    const int tileM = nb >> 2, tileN = nb & 3;
    const int m0 = tileM * BM, n0 = tileN * BN;

    // ---- gload_lds staging (linear LDS dest + inverse-swizzled global src) ----
    const int sRow = lane >> 3;
    const int swzc = ((lane & 7) * 16) ^ ((sRow & 7) << 4);
    const unsigned short* gA0 = A  + (size_t)(m0 + w * 32 + sRow) * DM + (swzc >> 1);
    const unsigned short* gB0 = Bw + (size_t)(n0 + w * 48 + sRow) * DM + (swzc >> 1);

    auto STAGE_A = [&](int buf, int kt) {
        #pragma unroll
        for (int j = 0; j < 4; ++j)
            gload_lds16(gA0 + (size_t)j * 8 * DM + kt * 64,
                        &Aa[buf][(w * 32 + j * 8) * 64]);
    };
    auto STAGE_B = [&](int buf, int kt) {
        #pragma unroll
        for (int j = 0; j < 6; ++j)
            gload_lds16(gB0 + (size_t)j * 8 * DM + kt * 64,
                        &Bb[buf][(w * 48 + j * 8) * 64]);
    };

    // ---- reg-staging state (XF>0) ----
    const int rRow0 = w * 32 + (lane >> 3);
    const unsigned short* gAr = A + (size_t)(m0 + rRow0) * DM + (lane & 7) * 8;
    const int wrswz = (lane >> 3) << 4;
    ushort8 aldr0[4], aldr1[4];       // XF==1/2
    ushort8 aldp0[4], aldp1[4];       // XF==2 (pos)
    f32x4   aldf0[4][2], aldf1[4][2]; // XF==3

    const int frow = lane & 15;
    const int fq16 = (lane >> 4) * 16;
    const int rswz = (lane & 7) << 4;

    f32x4 acc[8][3] = {};
    short8 breg[3];

    // ---- prologue ----
    if (XF == 0) {
        STAGE_A(0, 0);
        STAGE_B(0, 0);
        VM0
        BARR
    } else {
        ALOADM(0, 0)
        ALOADM(1, 1)
        STAGE_B(0, 0);
        XFORMM(0, 0, 0)
        VM0
        LGKM0
        BARR
    }

    if (XF == 0) {
        #pragma unroll
        for (int kt = 0; kt < NKT3; ++kt) {
            const int cb = kt & 1, nbuf = cb ^ 1;
            PH(cb, cb, 0, 0, 1, { if (kt < 11) STAGE_B(nbuf, kt + 1); }, {})
            PH(cb, cb, 1, 0, 0, { if (kt < 11) STAGE_A(nbuf, kt + 1); }, {})
            PH(cb, cb, 0, 1, 1, {}, {})
            if (kt < 11) { PH(cb, cb, 1, 1, 0, {}, { VM0 }) }
            else         { PH(cb, cb, 1, 1, 0, {}, {}) }
        }
    } else {
        for (int kp = 0; kp < 6; ++kp) {
            const int kte = 2 * kp;       // even tile: read buf0, load set0, xform set1
            XTILE(kte, 0, 0, 1)
            const int kto = kte + 1;      // odd tile: read buf1, load set1, xform set0
            XTILE(kto, 1, 1, 0)
        }
    }

    // ---- epilogue ----
    const int crow = (lane >> 4) * 4;
    const int ccol = lane & 15;
    const int nbase = n0 + wc * 48;

    float bv[3];
    #pragma unroll
    for (int j = 0; j < 3; ++j) bv[j] = bias[nbase + j * 16 + ccol];

    if (EPI == 0) {
        unsigned short* O = (unsigned short*)outp;
        #pragma unroll
        for (int mi = 0; mi < 8; ++mi) {
            #pragma unroll
            for (int r = 0; r < 4; ++r) {
                int m = m0 + mi * 16 + crow + r;
                unsigned short* orow = O + (size_t)m * DM + nbase + ccol;
                #pragma unroll
                for (int j = 0; j < 3; ++j)
                    orow[j * 16] = f2bf(fmaxf(acc[mi][j][r] + bv[j], 0.0f));
            }
        }
    }

    if (EPI == 2) {
        float* O = (float*)outp;
        #pragma unroll
        for (int mi = 0; mi < 8; ++mi) {
            #pragma unroll
            for (int r = 0; r < 4; ++r) {
                int m = m0 + mi * 16 + crow + r;
                int mo = (m & ~255) | invp[m];
                float* orow = O + (size_t)mo * DM + nbase + ccol;
                #pragma unroll
                for (int j = 0; j < 3; ++j)
                    orow[j * 16] = acc[mi][j][r] + bv[j];
            }
        }
    }

    if (EPI == 1) {
        unsigned short* O = (unsigned short*)outp;
        #pragma unroll
        for (int mi = 0; mi < 8; ++mi) {
            #pragma unroll
            for (int r = 0; r < 4; ++r) {
                int m = m0 + mi * 16 + crow + r;
                unsigned short* orow = O + (size_t)m * DM + nbase + ccol;
                #pragma unroll
                for (int j = 0; j < 3; ++j)
                    orow[j * 16] = f2bf(acc[mi][j][r] + bv[j]);
            }
        }
        // deterministic BN column partials (this wave: 128 rows x 48 cols)
        #pragma unroll
        for (int j = 0; j < 3; ++j) {
            float s = 0.f, q = 0.f;
            #pragma unroll
            for (int mi = 0; mi < 8; ++mi)
                #pragma unroll
                for (int r = 0; r < 4; ++r) {
                    float v = acc[mi][j][r] + bv[j];
                    s += v; q += v * v;
                }
            s += __shfl_xor(s, 16); s += __shfl_xor(s, 32);
            q += __shfl_xor(q, 16); q += __shfl_xor(q, 32);
            if (lane < 16) {
                int c = nbase + j * 16 + lane;
                bnpart[(size_t)c * 128 + tileM]        = s;
                bnpart[QOFF + (size_t)c * 128 + tileM] = q;
            }
        }
    }
}

// ---------------- BN finalize: reduce 128 partials -> scale/shift ----------------
__global__ void bn_stats(const float* __restrict__ part, const float* __restrict__ gamma,
                         const float* __restrict__ beta, float* __restrict__ ss)
{
    int c = blockIdx.x * 256 + threadIdx.x;   // 768
    const float* ps = part + (size_t)c * 128;
    const float* pq = part + QOFF + (size_t)c * 128;
    float s = 0.f, q = 0.f;
    #pragma unroll 8
    for (int i = 0; i < 128; ++i) { s += ps[i]; q += pq[i]; }
    float mu  = s * (1.0f / 16384.0f);
    float var = q * (1.0f / 16384.0f) - mu * mu;
    float scale = rsqrtf(var + 1e-5f) * gamma[c];
    ss[c] = scale;
    ss[DM + c] = beta[c] - mu * scale;
}

extern "C" void kernel_launch(void* const* d_in, const int* in_sizes, int n_in,
                              void* d_out, int out_size, void* d_ws, size_t ws_size,
                              hipStream_t stream)
{
    (void)in_sizes; (void)n_in; (void)out_size; (void)ws_size;

    const float* x       = (const float*)d_in[0];
    const float* conv0_w = (const float*)d_in[1];
    const float* conv0_b = (const float*)d_in[2];
    const float* w1      = (const float*)d_in[3];
    const float* b1      = (const float*)d_in[4];
    const float* gamma   = (const float*)d_in[5];
    const float* beta    = (const float*)d_in[6];
    const float* pos     = (const float*)d_in[7];
    const float* mixer_w = (const float*)d_in[8];
    const float* mixer_b = (const float*)d_in[9];
    const int*   perm    = (const int*)d_in[10];

    // workspace layout (~54 MB)
    unsigned short* actA = (unsigned short*)d_ws;               // 16384*768 bf16
    unsigned short* actB = actA + (size_t)M_TOT * DM;           // 16384*768 bf16
    unsigned short* wA   = actB + (size_t)M_TOT * DM;           // 768*768
    unsigned short* wD   = wA + DM * DM;                        // 3*768*768
    unsigned short* wM   = wD + 3 * DM * DM;                    // 768*768
    unsigned short* posb = wM + DM * DM;                        // 256*768 bf16
    float* bnpart = (float*)(posb + 256 * DM);                  // 2*128*768 f32
    float* ss     = bnpart + 2 * 128 * DM;                      // 2*768
    int*   invp   = (int*)(ss + 2 * DM);                        // 16384

    // weights->bf16 + invperm + pos->bf16
    prepw<<<3136, 256, 0, stream>>>(conv0_w, w1, mixer_w, perm, pos,
                                    wA, wD, wM, invp, posb);

    // g0: patch embed h0 = relu(im2col(x) @ W0^T + b0) -> actB  (im2col fused)
    gemm8p<0, 3><<<512, 256, 0, stream>>>(x, wA, conv0_b, actB, nullptr,
                                          nullptr, nullptr, nullptr);
    // g1: h1 = h0 @ w1[0]^T + b1[0] -> actA (+ partials)
    gemm8p<1, 0><<<512, 256, 0, stream>>>(actB, wD + 0 * (size_t)DM * DM, b1 + 0 * DM,
                                          actA, nullptr, bnpart, nullptr, nullptr);
    bn_stats<<<3, 256, 0, stream>>>(bnpart, gamma + 0 * DM, beta + 0 * DM, ss);
    // g2: h2 = relu(BN0(h1)) @ w1[1]^T + b1[1] -> actB (+ partials)
    gemm8p<1, 1><<<512, 256, 0, stream>>>(actA, wD + 1 * (size_t)DM * DM, b1 + 1 * DM,
                                          actB, nullptr, bnpart, ss, nullptr);
    bn_stats<<<3, 256, 0, stream>>>(bnpart, gamma + 1 * DM, beta + 1 * DM, ss);
    // g3: h3 = relu(BN1(h2)) @ w1[2]^T + b1[2] -> actA (+ partials)
    gemm8p<1, 1><<<512, 256, 0, stream>>>(actB, wD + 2 * (size_t)DM * DM, b1 + 2 * DM,
                                          actA, nullptr, bnpart, ss, nullptr);
    bn_stats<<<3, 256, 0, stream>>>(bnpart, gamma + 2 * DM, beta + 2 * DM, ss);
    // mixer: out = relu(relu(BN2(h3)) + posb) @ mixer_w^T + b, perm-scattered f32
    gemm8p<2, 2><<<512, 256, 0, stream>>>(actA, wM, mixer_b, d_out, invp,
                                          nullptr, ss, posb);
}

// Round 12
// 185.082 us; speedup vs baseline: 1.0867x; 1.0867x over previous
//
#include <hip/hip_runtime.h>
#include <hip/hip_bf16.h>
#include <stdint.h>

#define M_TOT 16384     // B*P = 64*256
#define DM 768
#define BM 128
#define BN 192
#define NKT3 12         // K / 64
#define QOFF (128 * DM) // sumsq offset in bnpart (floats)

typedef __attribute__((ext_vector_type(4))) float f32x4;
typedef __attribute__((ext_vector_type(8))) short short8;
typedef __attribute__((ext_vector_type(8))) unsigned short ushort8;
typedef __attribute__((ext_vector_type(4))) unsigned short ushort4v;

__device__ __forceinline__ unsigned short f2bf(float f) {
    union { float f; unsigned u; } v; v.f = f;
    unsigned r = v.u + 0x7fffu + ((v.u >> 16) & 1u);
    return (unsigned short)(r >> 16);
}
__device__ __forceinline__ float bf2f(unsigned short h) {
    union { unsigned u; float f; } v; v.u = ((unsigned)h) << 16;
    return v.f;
}

__device__ __forceinline__ void gload_lds16(const unsigned short* g, unsigned short* l) {
    __builtin_amdgcn_global_load_lds(
        (const __attribute__((address_space(1))) void*)g,
        (__attribute__((address_space(3))) void*)l, 16, 0, 0);
}

// ---------------- prep: weight cvt + inverse permutation ----------------
__global__ __launch_bounds__(256)
void prepw(const float* __restrict__ cw, const float* __restrict__ w1,
           const float* __restrict__ mw, const int* __restrict__ perm,
           unsigned short* __restrict__ wA, unsigned short* __restrict__ wD,
           unsigned short* __restrict__ wM, int* __restrict__ invp)
{
    int b = blockIdx.x;
    if (b < 2880) {
        int i = b * 256 + threadIdx.x;          // 737280 vec4 groups
        const float* src; unsigned short* dst; int off;
        if (i < 147456)              { src = cw; dst = wA; off = i; }
        else if (i < 147456+442368)  { src = w1; dst = wD; off = i - 147456; }
        else                         { src = mw; dst = wM; off = i - 589824; }
        f32x4 v = ((const f32x4*)src)[off];
        ushort4v o;
        o.x = f2bf(v.x); o.y = f2bf(v.y); o.z = f2bf(v.z); o.w = f2bf(v.w);
        ((ushort4v*)dst)[off] = o;
    } else {
        int i = (b - 2880) * 256 + threadIdx.x;  // 16384
        int bb = i >> 8;
        invp[(bb << 8) + perm[i]] = i & 255;
    }
}

// =====================================================================
// GEMM: out[M,768] = T(A)[M,768] * Bw[768,768]^T + bias
//   XF=0: A bf16, staged via global_load_lds; 1 barrier/K-tile loop
//   XF=1: A bf16 reg-staged (dbuf'd early ALOAD), T = relu(scl*a+shf)
//   XF=3: A = x f32, reg-staged im2col + cvt (patch embed)
// BM=128 x BN=192, BK=64, 4 waves 1M x 4N, wave tile 128x48,
// 16x16x32 MFMA, 2-deep dbuf, 80 KB LDS -> 2 blocks/CU.
// EPI 0: relu->bf16 ; EPI 1: ->bf16 + BN column partials ; EPI 2: perm-scatter->f32
// =====================================================================
#define VM0  asm volatile("s_waitcnt vmcnt(0)" ::: "memory");
#define LGKM0 asm volatile("s_waitcnt lgkmcnt(0)" ::: "memory");
#define BARR asm volatile("s_barrier" ::: "memory");

// 4-phase template (kept for XF=1/3 paths)
#define PH(AB, BB, MH, KS, LOADB, PRE, POST)                                     \
  {                                                                              \
    if (LOADB) {                                                                 \
      _Pragma("unroll")                                                          \
      for (int j = 0; j < 3; ++j)                                                \
        breg[j] = *(const short8*)((const char*)Bb + (size_t)(BB) * (BN*64*2) +  \
                  (wc * 48 + j * 16 + frow) * 128 + (((KS) * 64 + fq16) ^ rswz));\
    }                                                                            \
    short8 af[4];                                                                \
    _Pragma("unroll")                                                            \
    for (int i = 0; i < 4; ++i)                                                  \
      af[i] = *(const short8*)((const char*)Aa + (size_t)(AB) * (BM*64*2) +      \
              ((MH) * 64 + i * 16 + frow) * 128 +                                \
              (((KS) * 64 + fq16) ^ rswz));                                      \
    PRE;                                                                         \
    __builtin_amdgcn_s_setprio(1);                                               \
    _Pragma("unroll")                                                            \
    for (int i = 0; i < 4; ++i)                                                  \
      _Pragma("unroll")                                                          \
      for (int j = 0; j < 3; ++j)                                                \
        acc[(MH) * 4 + i][j] = __builtin_amdgcn_mfma_f32_16x16x32_bf16(          \
            af[i], breg[j], acc[(MH) * 4 + i][j], 0, 0, 0);                      \
    __builtin_amdgcn_s_setprio(0);                                               \
    POST;                                                                        \
    BARR                                                                         \
  }

// half-K-tile cluster for the 1-barrier XF=0 loop: 11 ds_reads + 24 MFMA
#define KHALF(CB, KS)                                                            \
  {                                                                              \
    short8 a8[8], b3[3];                                                         \
    _Pragma("unroll")                                                            \
    for (int i = 0; i < 8; ++i)                                                  \
      a8[i] = *(const short8*)((const char*)Aa + (size_t)(CB) * (BM*64*2) +      \
              (i * 16 + frow) * 128 + (((KS) * 64 + fq16) ^ rswz));              \
    _Pragma("unroll")                                                            \
    for (int j = 0; j < 3; ++j)                                                  \
      b3[j] = *(const short8*)((const char*)Bb + (size_t)(CB) * (BN*64*2) +      \
              (wc * 48 + j * 16 + frow) * 128 + (((KS) * 64 + fq16) ^ rswz));    \
    if (KS == 0 && ktv < 11) { STAGE_B(CB ^ 1, ktv + 1); STAGE_A(CB ^ 1, ktv + 1); } \
    __builtin_amdgcn_s_setprio(1);                                               \
    _Pragma("unroll")                                                            \
    for (int i = 0; i < 8; ++i)                                                  \
      _Pragma("unroll")                                                          \
      for (int j = 0; j < 3; ++j)                                                \
        acc[i][j] = __builtin_amdgcn_mfma_f32_16x16x32_bf16(                     \
            a8[i], b3[j], acc[i][j], 0, 0, 0);                                   \
    __builtin_amdgcn_s_setprio(0);                                               \
  }

// reg-staging: load into named set S (static indexing, rule #20)
#define ALOADM(t, S)                                                             \
  {                                                                              \
    if (XF == 3) {                                                               \
      const int c  = (t) >> 2;                                                   \
      const int r  = ((t) & 3) * 64 + (lane & 7) * 8;                            \
      const int kh = r >> 4;                                                     \
      const int kw0 = r & 15;                                                    \
      _Pragma("unroll")                                                          \
      for (int j = 0; j < 4; ++j) {                                              \
        int m = m0 + rRow0 + j * 8;                                              \
        int b = m >> 8, p = m & 255;                                             \
        const float* src = X + ((((size_t)b * 3 + c) * 256 + (p >> 4) * 16 + kh) \
                                * 256 + (p & 15) * 16 + kw0);                    \
        aldf##S[j][0] = *(const f32x4*)src;                                      \
        aldf##S[j][1] = *(const f32x4*)(src + 4);                                \
      }                                                                          \
    } else {                                                                     \
      _Pragma("unroll")                                                          \
      for (int j = 0; j < 4; ++j)                                                \
        aldr##S[j] = *(const ushort8*)(gAr + (size_t)j * 8 * DM + (t) * 64);     \
    }                                                                            \
  }

#define XFORMM(t, tb, S)                                                         \
  {                                                                              \
    if (XF == 3) {                                                               \
      _Pragma("unroll")                                                          \
      for (int j = 0; j < 4; ++j) {                                              \
        int row = rRow0 + j * 8;                                                 \
        ushort8 o;                                                               \
        _Pragma("unroll")                                                        \
        for (int e = 0; e < 8; ++e)                                              \
          o[e] = f2bf((e < 4) ? aldf##S[j][0][e] : aldf##S[j][1][e - 4]);        \
        *(ushort8*)((char*)Aa + (size_t)(tb) * (BM*64*2) + row * 128 +           \
                    (((lane & 7) * 16) ^ wrswz)) = o;                            \
      }                                                                          \
    } else {                                                                     \
      const int k0 = (t) * 64 + (lane & 7) * 8;                                  \
      f32x4 sa = *(const f32x4*)(ssA + k0);                                      \
      f32x4 sb = *(const f32x4*)(ssA + k0 + 4);                                  \
      f32x4 ha = *(const f32x4*)(ssA + DM + k0);                                 \
      f32x4 hb = *(const f32x4*)(ssA + DM + k0 + 4);                             \
      _Pragma("unroll")                                                          \
      for (int j = 0; j < 4; ++j) {                                              \
        int row = rRow0 + j * 8;                                                 \
        ushort8 u = aldr##S[j];                                                  \
        ushort8 o;                                                               \
        _Pragma("unroll")                                                        \
        for (int e = 0; e < 8; ++e) {                                            \
          float f = bf2f(u[e]);                                                  \
          float sc = (e < 4) ? sa[e] : sb[e - 4];                                \
          float sh = (e < 4) ? ha[e] : hb[e - 4];                                \
          o[e] = f2bf(fmaxf(fmaf(sc, f, sh), 0.0f));                             \
        }                                                                        \
        *(ushort8*)((char*)Aa + (size_t)(tb) * (BM*64*2) + row * 128 +           \
                    (((lane & 7) * 16) ^ wrswz)) = o;                            \
      }                                                                          \
    }                                                                            \
  }

// one K-tile for the reg-staged path; CB = read buffer (0 even tile, 1 odd),
// LS = aldr set loaded this tile, XS = set transformed this tile
#define XTILE(kt, CB, LS, XS)                                                    \
    PH(CB, CB, 0, 0, 1, { if ((kt) < 11) STAGE_B((CB) ^ 1, (kt) + 1);            \
                          if ((kt) < 10) ALOADM((kt) + 2, LS) }, {})             \
    PH(CB, CB, 1, 0, 0, { if ((kt) < 11) XFORMM((kt) + 1, (CB) ^ 1, XS) },       \
                        { if ((kt) < 11) LGKM0 })                                \
    PH(CB, CB, 0, 1, 1, {}, {})                                                  \
    if ((kt) < 11) { PH(CB, CB, 1, 1, 0, {}, { VM0 }) }                          \
    else           { PH(CB, CB, 1, 1, 0, {}, {}) }

template<int EPI, int XF>
__global__ __launch_bounds__(256, 2)
void gemm8p(const void* __restrict__ Asrc,
            const unsigned short* __restrict__ Bw,
            const float* __restrict__ bias,
            void* __restrict__ outp,
            const int* __restrict__ invp,
            float* __restrict__ bnpart,
            const float* __restrict__ ssA)     // [scale 768 | shift 768]
{
    __shared__ unsigned short Aa[2][BM * 64];   // 2 x 16 KB
    __shared__ unsigned short Bb[2][BN * 64];   // 2 x 24 KB  (total 80 KB)

    const unsigned short* A = (const unsigned short*)Asrc;
    const float* X = (const float*)Asrc;

    const int tid  = threadIdx.x;
    const int w    = tid >> 6;                  // 0..3
    const int lane = tid & 63;
    const int wc = w;                           // 1M x 4N

    // bijective XCD swizzle over exactly 512 workgroups (64 per XCD)
    int bid = blockIdx.x;
    int nb  = (bid & 7) * 64 + (bid >> 3);
    const int tileM = nb >> 2, tileN = nb & 3;
    const int m0 = tileM * BM, n0 = tileN * BN;

    // ---- gload_lds staging (linear LDS dest + inverse-swizzled global src) ----
    const int sRow = lane >> 3;
    const int swzc = ((lane & 7) * 16) ^ ((sRow & 7) << 4);
    const unsigned short* gA0 = A  + (size_t)(m0 + w * 32 + sRow) * DM + (swzc >> 1);
    const unsigned short* gB0 = Bw + (size_t)(n0 + w * 48 + sRow) * DM + (swzc >> 1);

    auto STAGE_A = [&](int buf, int kt) {
        #pragma unroll
        for (int j = 0; j < 4; ++j)
            gload_lds16(gA0 + (size_t)j * 8 * DM + kt * 64,
                        &Aa[buf][(w * 32 + j * 8) * 64]);
    };
    auto STAGE_B = [&](int buf, int kt) {
        #pragma unroll
        for (int j = 0; j < 6; ++j)
            gload_lds16(gB0 + (size_t)j * 8 * DM + kt * 64,
                        &Bb[buf][(w * 48 + j * 8) * 64]);
    };

    // ---- reg-staging state (XF>0) ----
    const int rRow0 = w * 32 + (lane >> 3);
    const unsigned short* gAr = A + (size_t)(m0 + rRow0) * DM + (lane & 7) * 8;
    const int wrswz = (lane >> 3) << 4;
    ushort8 aldr0[4], aldr1[4];       // XF==1
    f32x4   aldf0[4][2], aldf1[4][2]; // XF==3

    const int frow = lane & 15;
    const int fq16 = (lane >> 4) * 16;
    const int rswz = (lane & 7) << 4;

    f32x4 acc[8][3] = {};
    short8 breg[3];

    // ---- prologue ----
    if (XF == 0) {
        STAGE_A(0, 0);
        STAGE_B(0, 0);
        VM0
        BARR
    } else {
        ALOADM(0, 0)
        ALOADM(1, 1)
        STAGE_B(0, 0);
        XFORMM(0, 0, 0)
        VM0
        LGKM0
        BARR
    }

    if (XF == 0) {
        // 1-barrier-per-K-tile loop: 2x(11 ds_read + 24 MFMA) + VM0 + BARR
        #pragma unroll
        for (int ktv = 0; ktv < NKT3; ++ktv) {
            const int cb = ktv & 1;
            KHALF(cb, 0)
            KHALF(cb, 1)
            if (ktv < 11) { VM0 }
            BARR
        }
    } else {
        for (int kp = 0; kp < 6; ++kp) {
            const int kte = 2 * kp;       // even tile: read buf0, load set0, xform set1
            XTILE(kte, 0, 0, 1)
            const int kto = kte + 1;      // odd tile: read buf1, load set1, xform set0
            XTILE(kto, 1, 1, 0)
        }
    }

    // ---- epilogue ----
    const int crow = (lane >> 4) * 4;
    const int ccol = lane & 15;
    const int nbase = n0 + wc * 48;

    float bv[3];
    #pragma unroll
    for (int j = 0; j < 3; ++j) bv[j] = bias[nbase + j * 16 + ccol];

    if (EPI == 0) {
        unsigned short* O = (unsigned short*)outp;
        #pragma unroll
        for (int mi = 0; mi < 8; ++mi) {
            #pragma unroll
            for (int r = 0; r < 4; ++r) {
                int m = m0 + mi * 16 + crow + r;
                unsigned short* orow = O + (size_t)m * DM + nbase + ccol;
                #pragma unroll
                for (int j = 0; j < 3; ++j)
                    orow[j * 16] = f2bf(fmaxf(acc[mi][j][r] + bv[j], 0.0f));
            }
        }
    }

    if (EPI == 2) {
        float* O = (float*)outp;
        #pragma unroll
        for (int mi = 0; mi < 8; ++mi) {
            #pragma unroll
            for (int r = 0; r < 4; ++r) {
                int m = m0 + mi * 16 + crow + r;
                int mo = (m & ~255) | invp[m];
                float* orow = O + (size_t)mo * DM + nbase + ccol;
                #pragma unroll
                for (int j = 0; j < 3; ++j)
                    orow[j * 16] = acc[mi][j][r] + bv[j];
            }
        }
    }

    if (EPI == 1) {
        unsigned short* O = (unsigned short*)outp;
        #pragma unroll
        for (int mi = 0; mi < 8; ++mi) {
            #pragma unroll
            for (int r = 0; r < 4; ++r) {
                int m = m0 + mi * 16 + crow + r;
                unsigned short* orow = O + (size_t)m * DM + nbase + ccol;
                #pragma unroll
                for (int j = 0; j < 3; ++j)
                    orow[j * 16] = f2bf(acc[mi][j][r] + bv[j]);
            }
        }
        // deterministic BN column partials (this wave: 128 rows x 48 cols)
        #pragma unroll
        for (int j = 0; j < 3; ++j) {
            float s = 0.f, q = 0.f;
            #pragma unroll
            for (int mi = 0; mi < 8; ++mi)
                #pragma unroll
                for (int r = 0; r < 4; ++r) {
                    float v = acc[mi][j][r] + bv[j];
                    s += v; q += v * v;
                }
            s += __shfl_xor(s, 16); s += __shfl_xor(s, 32);
            q += __shfl_xor(q, 16); q += __shfl_xor(q, 32);
            if (lane < 16) {
                int c = nbase + j * 16 + lane;
                bnpart[(size_t)c * 128 + tileM]        = s;
                bnpart[QOFF + (size_t)c * 128 + tileM] = q;
            }
        }
    }
}

// ---------------- BN finalize: reduce 128 partials -> scale/shift ----------------
__global__ void bn_stats(const float* __restrict__ part, const float* __restrict__ gamma,
                         const float* __restrict__ beta, float* __restrict__ ss)
{
    int c = blockIdx.x * 256 + threadIdx.x;   // 768
    const float* ps = part + (size_t)c * 128;
    const float* pq = part + QOFF + (size_t)c * 128;
    float s = 0.f, q = 0.f;
    #pragma unroll 8
    for (int i = 0; i < 128; ++i) { s += ps[i]; q += pq[i]; }
    float mu  = s * (1.0f / 16384.0f);
    float var = q * (1.0f / 16384.0f) - mu * mu;
    float scale = rsqrtf(var + 1e-5f) * gamma[c];
    ss[c] = scale;
    ss[DM + c] = beta[c] - mu * scale;
}

// ---------------- BN apply + pos + relu (mixer input) ----------------
__global__ __launch_bounds__(256)
void bnpos_apply(const unsigned short* __restrict__ hin, const float* __restrict__ ss,
                 const float* __restrict__ pos, unsigned short* __restrict__ hout)
{
    __shared__ float sc[DM], sh[DM];
    const int t = threadIdx.x;
    #pragma unroll
    for (int i = 0; i < 3; ++i) {
        sc[t + i * 256] = ss[t + i * 256];
        sh[t + i * 256] = ss[DM + t + i * 256];
    }
    __syncthreads();

    int g = blockIdx.x * 256 + t;           // 16384*96 vec8 groups
    int row = g / 96;
    int c0 = (g - row * 96) * 8;
    const short8 v = *(const short8*)(hin + (size_t)row * DM + c0);
    short8 o;
    #pragma unroll
    for (int e = 0; e < 8; ++e) {
        float xv = bf2f((unsigned short)v[e]);
        float y = fmaxf(xv * sc[c0 + e] + sh[c0 + e], 0.0f);
        y = fmaxf(y + pos[(row & 255) * DM + c0 + e], 0.0f);
        o[e] = (short)f2bf(y);
    }
    *(short8*)(hout + (size_t)row * DM + c0) = o;
}

extern "C" void kernel_launch(void* const* d_in, const int* in_sizes, int n_in,
                              void* d_out, int out_size, void* d_ws, size_t ws_size,
                              hipStream_t stream)
{
    (void)in_sizes; (void)n_in; (void)out_size; (void)ws_size;

    const float* x       = (const float*)d_in[0];
    const float* conv0_w = (const float*)d_in[1];
    const float* conv0_b = (const float*)d_in[2];
    const float* w1      = (const float*)d_in[3];
    const float* b1      = (const float*)d_in[4];
    const float* gamma   = (const float*)d_in[5];
    const float* beta    = (const float*)d_in[6];
    const float* pos     = (const float*)d_in[7];
    const float* mixer_w = (const float*)d_in[8];
    const float* mixer_b = (const float*)d_in[9];
    const int*   perm    = (const int*)d_in[10];

    // workspace layout (~53 MB)
    unsigned short* actA = (unsigned short*)d_ws;               // 16384*768 bf16
    unsigned short* actB = actA + (size_t)M_TOT * DM;           // 16384*768 bf16
    unsigned short* wA   = actB + (size_t)M_TOT * DM;           // 768*768
    unsigned short* wD   = wA + DM * DM;                        // 3*768*768
    unsigned short* wM   = wD + 3 * DM * DM;                    // 768*768
    float* bnpart = (float*)(wM + DM * DM);                     // 2*128*768 f32
    float* ss     = bnpart + 2 * 128 * DM;                      // 2*768
    int*   invp   = (int*)(ss + 2 * DM);                        // 16384

    // weights->bf16 + invperm
    prepw<<<2944, 256, 0, stream>>>(conv0_w, w1, mixer_w, perm, wA, wD, wM, invp);

    // g0: patch embed h0 = relu(im2col(x) @ W0^T + b0) -> actB  (im2col fused)
    gemm8p<0, 3><<<512, 256, 0, stream>>>(x, wA, conv0_b, actB, nullptr,
                                          nullptr, nullptr);
    // g1: h1 = h0 @ w1[0]^T + b1[0] -> actA (+ partials)
    gemm8p<1, 0><<<512, 256, 0, stream>>>(actB, wD + 0 * (size_t)DM * DM, b1 + 0 * DM,
                                          actA, nullptr, bnpart, nullptr);
    bn_stats<<<3, 256, 0, stream>>>(bnpart, gamma + 0 * DM, beta + 0 * DM, ss);
    // g2: h2 = relu(BN0(h1)) @ w1[1]^T + b1[1] -> actB (+ partials)
    gemm8p<1, 1><<<512, 256, 0, stream>>>(actA, wD + 1 * (size_t)DM * DM, b1 + 1 * DM,
                                          actB, nullptr, bnpart, ss);
    bn_stats<<<3, 256, 0, stream>>>(bnpart, gamma + 1 * DM, beta + 1 * DM, ss);
    // g3: h3 = relu(BN1(h2)) @ w1[2]^T + b1[2] -> actA (+ partials)
    gemm8p<1, 1><<<512, 256, 0, stream>>>(actB, wD + 2 * (size_t)DM * DM, b1 + 2 * DM,
                                          actA, nullptr, bnpart, ss);
    bn_stats<<<3, 256, 0, stream>>>(bnpart, gamma + 2 * DM, beta + 2 * DM, ss);
    // mixer input: relu(relu(BN2(h3)) + pos) -> actB
    bnpos_apply<<<6144, 256, 0, stream>>>(actA, ss, pos, actB);
    // mixer: out = actB @ mixer_w^T + b, perm-scattered f32 (XF=0 path)
    gemm8p<2, 0><<<512, 256, 0, stream>>>(actB, wM, mixer_b, d_out, invp,
                                          nullptr, nullptr);
}